// Round 18
// baseline (195.800 us; speedup 1.0000x reference)
//
#include <hip/hip_runtime.h>

#define NWIN 4096
#define DIM 96
#define HEADS 6
#define NTOK 64

typedef __bf16 bf16x8 __attribute__((ext_vector_type(8)));
typedef __bf16 bf16x4 __attribute__((ext_vector_type(4)));
typedef short  s16x4  __attribute__((ext_vector_type(4)));
typedef float  f32x4  __attribute__((ext_vector_type(4)));
typedef int    i32x4  __attribute__((ext_vector_type(4)));

__device__ __forceinline__ f32x4 mfma32(bf16x8 a, bf16x8 b, f32x4 c) {
  return __builtin_amdgcn_mfma_f32_16x16x32_bf16(a, b, c, 0, 0, 0);
}
// K=16 MFMA. Fragment algebra (verified r7-r17; r17 first-pass validated the
// full transposed chain at absmax 1.22e-4):
//  * A/B frag lane(l16,lq) holds row/col=l16, k=4lq+e — identical to the
//    W*X^T D-frag (row=4lq+r, col=l16), so K,Q,V stay in registers.
//  * QK^T output s[a] = S[q=l16][kv=16a+4lq+r] — IS the PV B-frag (col=q).
//  * O^T = sum_a mfma16k(A=vb4[a], B=pa[a]) gives D col=l16=q,
//    row=4lq+r=feature — which IS the proj A-frag (row=token, k=feat).
//    proj chains in registers: pacc[bq][c] += mfma16k(oat, wp_chunk, .),
//    head-summed by MFMA C-accumulation. NO ao buffer, NO barriers.
__device__ __forceinline__ f32x4 mfma16k(bf16x4 a, bf16x4 b, f32x4 c) {
  return __builtin_amdgcn_mfma_f32_16x16x16bf16_1k(
      __builtin_bit_cast(s16x4, a), __builtin_bit_cast(s16x4, b), c, 0, 0, 0);
}

__device__ __forceinline__ bf16x8 cvt8(const float* p) {
  const float4* q = (const float4*)p;
  float4 a = q[0];
  float4 b = q[1];
  bf16x8 r;
  r[0] = (__bf16)a.x; r[1] = (__bf16)a.y; r[2] = (__bf16)a.z; r[3] = (__bf16)a.w;
  r[4] = (__bf16)b.x; r[5] = (__bf16)b.y; r[6] = (__bf16)b.z; r[7] = (__bf16)b.w;
  return r;
}

__device__ __forceinline__ bf16x4 cvt4(const float* p) {
  const float4 t = *(const float4*)p;
  bf16x4 r;
  r[0] = (__bf16)t.x; r[1] = (__bf16)t.y; r[2] = (__bf16)t.z; r[3] = (__bf16)t.w;
  return r;
}

// r18: ONE KERNEL, ZERO workspace, ZERO cross-kernel edges. r17's post-timing
// divergence (3.9e-3 — bias-magnitude corruption) implicated the
// prep_kernel->d_ws->win_attn dependency replayed against the harness's
// one-time d_ws poison (per-XCD L2s are not cross-coherent; correctness must
// not depend on inter-kernel cache timing). Everything r17's prep staged is
// now derived in-kernel from the immutable inputs:
//  * weights: cvt8/cvt4 on the f32 tensors (L2-resident, ~+4% VALU)
//  * bias: int4 rpi load + 4 rpb gathers per (head,bq,a) — L1-resident tables
// Structure: one wave = one window (64-thread blocks, grid 4096), the
// transposed-PV/proj register chain, no LDS after staging, no barriers
// except one __syncthreads() (compiler-ordered) after the x staging.
// setprio and inline-asm waitcnts removed — nothing exotic remains.
// launch_bounds(64,2): 256-reg budget >= ~190 peak (r3/r6/r7/r11-13 lesson:
// never budget below the live set).
__global__ __launch_bounds__(64, 2) void win_attn(
    const float* __restrict__ x,
    const int* __restrict__ rpi,
    const float* __restrict__ qkv_w,
    const float* __restrict__ qkv_b,
    const float* __restrict__ proj_w,
    const float* __restrict__ proj_b,
    const float* __restrict__ rpb,
    float* __restrict__ out) {
  __shared__ __align__(16) __bf16 xfrag[6144];  // 12 frags * 512 bf16

  const int lane = (int)threadIdx.x & 63;
  const int l16 = lane & 15;
  const int lq = lane >> 4;
  const int b = (int)blockIdx.x;

  const float* xw = x + (size_t)b * (NTOK * DIM);

  // ---- stage x fragments (single wave stages all 12) ----
#pragma unroll
  for (int f = 0; f < 12; ++f) {
    const int mt = f / 3, ks = f % 3;  // compile-time
    bf16x8 v = cvt8(xw + (16 * mt + l16) * DIM + 32 * ks + 8 * lq);
    *(bf16x8*)(xfrag + (f * 64 + lane) * 8) = v;
  }
  __syncthreads();  // 1 wave: compiles to waitcnt(+barrier); compiler-ordered

#define XV(mt, ks) (*(const bf16x8*)(xfrag + (((mt) * 3 + (ks)) * 64 + lane) * 8))

  // ---- proj accumulators, bias as C-init; live across all heads ----
  f32x4 pacc[4][6];
#pragma unroll
  for (int c = 0; c < 6; ++c) {
    const float pb = proj_b[16 * c + l16];
#pragma unroll
    for (int bq = 0; bq < 4; ++bq) {
      f32x4 t = {pb, pb, pb, pb};
      pacc[bq][c] = t;
    }
  }

  // ---- 6 heads sequentially; NO unroll (register discipline) ----
#pragma unroll 1
  for (int h = 0; h < HEADS; ++h) {
    // K phase: D = Wk * X^T + kb (bias C-init); D-frag stays in regs
    bf16x4 kb[4];
    {
      const int frow = (HEADS + h) * 16;
      bf16x8 wb[3];
#pragma unroll
      for (int ks = 0; ks < 3; ++ks)
        wb[ks] = cvt8(qkv_w + (frow + l16) * 96 + 32 * ks + 8 * lq);
      const float4 kb4 = *(const float4*)(qkv_b + frow + 4 * lq);
#pragma unroll
      for (int mt = 0; mt < 4; ++mt) {
        f32x4 acc = {kb4.x, kb4.y, kb4.z, kb4.w};
#pragma unroll
        for (int ks = 0; ks < 3; ++ks) acc = mfma32(wb[ks], XV(mt, ks), acc);
#pragma unroll
        for (int r = 0; r < 4; ++r) kb[mt][r] = (__bf16)acc[r];
      }
    }

    // Q phase: D = (Wq * X^T + qb) * 0.25; registers only
    bf16x4 qv4[4];
    {
      const int frow = h * 16;
      bf16x8 wb[3];
#pragma unroll
      for (int ks = 0; ks < 3; ++ks)
        wb[ks] = cvt8(qkv_w + (frow + l16) * 96 + 32 * ks + 8 * lq);
      const float4 qb4 = *(const float4*)(qkv_b + frow + 4 * lq);
#pragma unroll
      for (int mt = 0; mt < 4; ++mt) {
        f32x4 acc = {qb4.x, qb4.y, qb4.z, qb4.w};
#pragma unroll
        for (int ks = 0; ks < 3; ++ks) acc = mfma32(wb[ks], XV(mt, ks), acc);
#pragma unroll
        for (int r = 0; r < 4; ++r) qv4[mt][r] = (__bf16)(acc[r] * 0.25f);
      }
    }

    // V phase: D = X * Wv^T + vb; D-frag mt=a IS the O^T A-frag chunk a
    bf16x4 vb4[4];
    {
      const int frow = (2 * HEADS + h) * 16;
      bf16x8 wb[3];
#pragma unroll
      for (int ks = 0; ks < 3; ++ks)
        wb[ks] = cvt8(qkv_w + (frow + l16) * 96 + 32 * ks + 8 * lq);
      const float vb = qkv_b[frow + l16];
#pragma unroll
      for (int mt = 0; mt < 4; ++mt) {
        f32x4 acc = {vb, vb, vb, vb};
#pragma unroll
        for (int ks = 0; ks < 3; ++ks) acc = mfma32(XV(mt, ks), wb[ks], acc);
#pragma unroll
        for (int r = 0; r < 4; ++r) vb4[mt][r] = (__bf16)acc[r];
      }
    }

    // proj weight chunks for this head: B[col=16c+l16][k=16h+4lq+e]
    bf16x4 wpch[6];
#pragma unroll
    for (int c = 0; c < 6; ++c)
      wpch[c] = cvt4(proj_w + (16 * c + l16) * 96 + 16 * h + 4 * lq);

#pragma unroll
    for (int bq = 0; bq < 4; ++bq) {
      // bias gather in-kernel: rpi row (16bq+l16), cols 16a+4lq+{0..3}
      // (int4 load, 16B-aligned); rpb L1-resident.
      f32x4 s[4];
#pragma unroll
      for (int a = 0; a < 4; ++a) {
        const i32x4 idx =
            *(const i32x4*)(rpi + (16 * bq + l16) * 64 + 16 * a + 4 * lq);
#pragma unroll
        for (int r = 0; r < 4; ++r) s[a][r] = rpb[idx[r] * HEADS + h];
      }

      // QK^T: S^T = K * Q^T with bias as C-init
#pragma unroll
      for (int a = 0; a < 4; ++a) s[a] = mfma16k(kb[a], qv4[bq], s[a]);

      // unnormalized softmax (|logits|<<1 -> exp direct); tsum from the
      // bf16-rounded P so numerator/denominator match (r9 lesson)
      float tp[4];
      bf16x4 pa[4];
#pragma unroll
      for (int a = 0; a < 4; ++a) {
        float t0 = 0.f;
#pragma unroll
        for (int r = 0; r < 4; ++r) {
          const __bf16 pe = (__bf16)__expf(s[a][r]);
          pa[a][r] = pe;
          t0 += (float)pe;
        }
        tp[a] = t0;
      }
      float tsum = (tp[0] + tp[1]) + (tp[2] + tp[3]);
      tsum += __shfl_xor(tsum, 16);
      tsum += __shfl_xor(tsum, 32);  // rcp latency hides under O^T below

      // O^T = sum_a V^T_chunk[a] * P^T_chunk[a]: D col=l16=q, row=4lq+r=feat
      f32x4 ot = {0.f, 0.f, 0.f, 0.f};
#pragma unroll
      for (int a = 0; a < 4; ++a) ot = mfma16k(vb4[a], pa[a], ot);

      const float rv = 1.0f / tsum;  // per-q (lane-local), same for all r
      bf16x4 oat;
#pragma unroll
      for (int r = 0; r < 4; ++r) oat[r] = (__bf16)(ot[r] * rv);

      // proj: pacc[bq][c] += oat * Wp_chunk(h,c) — head-sum via MFMA C
#pragma unroll
      for (int c = 0; c < 6; ++c)
        pacc[bq][c] = mfma16k(oat, wpch[c], pacc[bq][c]);
    }
  }
#undef XV

  // ---- final store: D row=4lq+r -> token 16bq+4lq+r, col=l16 -> 16c+l16 ----
  float* outw = out + (size_t)b * (NTOK * DIM);
#pragma unroll
  for (int bq = 0; bq < 4; ++bq)
#pragma unroll
    for (int c = 0; c < 6; ++c)
#pragma unroll
      for (int r = 0; r < 4; ++r)
        outw[(16 * bq + 4 * lq + r) * 96 + 16 * c + l16] = pacc[bq][c][r];
}

extern "C" void kernel_launch(void* const* d_in, const int* in_sizes, int n_in,
                              void* d_out, int out_size, void* d_ws, size_t ws_size,
                              hipStream_t stream) {
  const float* x      = (const float*)d_in[0];
  const int*   rpi    = (const int*)d_in[1];
  const float* qkv_w  = (const float*)d_in[2];
  const float* qkv_b  = (const float*)d_in[3];
  const float* proj_w = (const float*)d_in[4];
  const float* proj_b = (const float*)d_in[5];
  const float* rpb    = (const float*)d_in[6];
  float* out = (float*)d_out;

  // Single kernel; d_ws intentionally unused (r17 lesson: no cross-kernel
  // workspace dependencies under graph replay).
  win_attn<<<NWIN, 64, 0, stream>>>(x, rpi, qkv_w, qkv_b, proj_w, proj_b,
                                    rpb, out);
}

// Round 19
// 86.475 us; speedup vs baseline: 2.2643x; 2.2643x over previous
//
#include <hip/hip_runtime.h>

#define NWIN 4096
#define DIM 96
#define HEADS 6
#define NTOK 64

typedef __bf16 bf16x8 __attribute__((ext_vector_type(8)));
typedef __bf16 bf16x4 __attribute__((ext_vector_type(4)));
typedef short  s16x4  __attribute__((ext_vector_type(4)));
typedef float  f32x4  __attribute__((ext_vector_type(4)));
typedef int    i32x4  __attribute__((ext_vector_type(4)));

// d_ws layout
#define WS_QKVW 0                   // 288*96 bf16 = 55296 B
#define WS_PROJW 55296              // 96*96 bf16  = 18432 B
#define WS_BIAS 73728               // 6*16*64 float4 = 98304 B (frag-ordered)
#define WS_TOTAL 172032

__device__ __forceinline__ f32x4 mfma32(bf16x8 a, bf16x8 b, f32x4 c) {
  return __builtin_amdgcn_mfma_f32_16x16x32_bf16(a, b, c, 0, 0, 0);
}
// K=16 MFMA. Fragment algebra (verified r7-r18; r17/r18 validated the full
// transposed chain end-to-end at absmax 1.22e-4):
//  * A/B frag lane(l16,lq) holds row/col=l16, k=4lq+e — identical to the
//    W*X^T D-frag (row=4lq+r, col=l16), so K,Q,V stay in registers.
//  * QK^T output s[a] = S[q=l16][kv=16a+4lq+r] — IS the PV B-frag (col=q).
//  * O^T = sum_a mfma16k(A=vb4[a], B=pa[a]) gives D col=l16=q,
//    row=4lq+r=feature — which IS the proj A-frag (row=token, k=feat).
//    proj chains in registers: pacc[bq][c] += mfma16k(oat, wp_chunk, .),
//    head-summed by MFMA C-accumulation. NO ao buffer, NO extra barriers.
__device__ __forceinline__ f32x4 mfma16k(bf16x4 a, bf16x4 b, f32x4 c) {
  return __builtin_amdgcn_mfma_f32_16x16x16bf16_1k(
      __builtin_bit_cast(s16x4, a), __builtin_bit_cast(s16x4, b), c, 0, 0, 0);
}

__device__ __forceinline__ bf16x8 cvt8(const float* p) {
  const float4* q = (const float4*)p;
  float4 a = q[0];
  float4 b = q[1];
  bf16x8 r;
  r[0] = (__bf16)a.x; r[1] = (__bf16)a.y; r[2] = (__bf16)a.z; r[3] = (__bf16)a.w;
  r[4] = (__bf16)b.x; r[5] = (__bf16)b.y; r[6] = (__bf16)b.z; r[7] = (__bf16)b.w;
  return r;
}

__device__ __forceinline__ bf16x4 cvt4(const float* p) {
  const float4 t = *(const float4*)p;
  bf16x4 r;
  r[0] = (__bf16)t.x; r[1] = (__bf16)t.y; r[2] = (__bf16)t.z; r[3] = (__bf16)t.w;
  return r;
}

// Pre-pass: weights -> bf16; bias gathered into MFMA-fragment order:
// bias[((h*16 + bq*4 + a)*64 + lane)*4 + r] = rpb[rpi[qrow*64+kcol]*6+h]
// with qrow = 16*bq + (lane&15), kcol = 16*a + 4*(lane>>4) + r.
// (Proven stable under graph replay across r2/4/6/8/9/14/15/16.)
__global__ void prep_kernel(const float* __restrict__ qkv_w,
                            const float* __restrict__ proj_w,
                            const float* __restrict__ rpb,
                            const int* __restrict__ rpi,
                            char* __restrict__ ws) {
  int i = blockIdx.x * blockDim.x + threadIdx.x;
  __bf16* qw = (__bf16*)(ws + WS_QKVW);
  __bf16* pw = (__bf16*)(ws + WS_PROJW);
  float* bias = (float*)(ws + WS_BIAS);
  if (i < 288 * 96) qw[i] = (__bf16)qkv_w[i];
  int j = i - 288 * 96;
  if (j >= 0 && j < 96 * 96) pw[j] = (__bf16)proj_w[j];
  int t = i - (288 * 96 + 96 * 96);
  if (t >= 0 && t < HEADS * 16 * 64 * 4) {
    int r = t & 3;
    int lane = (t >> 2) & 63;
    int ba = (t >> 8) & 15;
    int h = t >> 12;
    int bq = ba >> 2, a = ba & 3;
    int l16 = lane & 15, lq = lane >> 4;
    int qrow = 16 * bq + l16;
    int kcol = 16 * a + 4 * lq + r;
    bias[t] = rpb[rpi[qrow * 64 + kcol] * HEADS + h];
  }
}

// r19: r17's fast structure (1 wave = 1 window, transposed-PV/proj register
// chain, single barrier) + r18's safe synchronization (__syncthreads, no
// setprio, no inline asm — r17's post-timing 1-bf16-ulp wobble was unique to
// the asm-lgkmcnt/setprio combo, rule #18) + the 8x-replay-proven ws staging
// (r18's in-kernel gather cost 3x: 384 serial rpb gathers on the QK^T path).
// launch_bounds(64,2): 256-reg budget >= ~190 peak (never under-budget:
// r3/r6/r7/r11-13 all spilled catastrophically from exactly that).
template <bool USE_WS>
__global__ __launch_bounds__(64, 2) void win_attn(
    const float* __restrict__ x,
    const int* __restrict__ rpi,
    const float* __restrict__ qkv_w,
    const float* __restrict__ qkv_b,
    const float* __restrict__ proj_w,
    const float* __restrict__ proj_b,
    const float* __restrict__ rpb,
    const char* __restrict__ ws,
    float* __restrict__ out) {
  __shared__ __align__(16) __bf16 xfrag[6144];  // 12 frags * 512 bf16

  const int lane = (int)threadIdx.x & 63;
  const int l16 = lane & 15;
  const int lq = lane >> 4;
  const int b = (int)blockIdx.x;

  const float* xw = x + (size_t)b * (NTOK * DIM);
  const __bf16* qwb = (const __bf16*)(ws + WS_QKVW);
  const __bf16* pwb = (const __bf16*)(ws + WS_PROJW);

  // ---- stage x fragments (single wave stages all 12) ----
#pragma unroll
  for (int f = 0; f < 12; ++f) {
    const int mt = f / 3, ks = f % 3;  // compile-time
    bf16x8 v = cvt8(xw + (16 * mt + l16) * DIM + 32 * ks + 8 * lq);
    *(bf16x8*)(xfrag + (f * 64 + lane) * 8) = v;
  }
  __syncthreads();  // compiler-ordered staging fence (r18-proven)

#define XV(mt, ks) (*(const bf16x8*)(xfrag + (((mt) * 3 + (ks)) * 64 + lane) * 8))

  // ---- proj accumulators, bias as C-init; live across all heads ----
  f32x4 pacc[4][6];
#pragma unroll
  for (int c = 0; c < 6; ++c) {
    const float pb = proj_b[16 * c + l16];
#pragma unroll
    for (int bq = 0; bq < 4; ++bq) {
      f32x4 t = {pb, pb, pb, pb};
      pacc[bq][c] = t;
    }
  }

  // ---- 6 heads sequentially; NO unroll (register discipline) ----
#pragma unroll 1
  for (int h = 0; h < HEADS; ++h) {
    // K phase: D = Wk * X^T + kb (bias C-init); D-frag stays in regs
    bf16x4 kb[4];
    {
      const int frow = (HEADS + h) * 16;
      bf16x8 wb[3];
#pragma unroll
      for (int ks = 0; ks < 3; ++ks) {
        if constexpr (USE_WS)
          wb[ks] = *(const bf16x8*)(qwb + (frow + l16) * 96 + 32 * ks + 8 * lq);
        else
          wb[ks] = cvt8(qkv_w + (frow + l16) * 96 + 32 * ks + 8 * lq);
      }
      const float4 kb4 = *(const float4*)(qkv_b + frow + 4 * lq);
#pragma unroll
      for (int mt = 0; mt < 4; ++mt) {
        f32x4 acc = {kb4.x, kb4.y, kb4.z, kb4.w};
#pragma unroll
        for (int ks = 0; ks < 3; ++ks) acc = mfma32(wb[ks], XV(mt, ks), acc);
#pragma unroll
        for (int r = 0; r < 4; ++r) kb[mt][r] = (__bf16)acc[r];
      }
    }

    // Q phase: D = (Wq * X^T + qb) * 0.25; registers only
    bf16x4 qv4[4];
    {
      const int frow = h * 16;
      bf16x8 wb[3];
#pragma unroll
      for (int ks = 0; ks < 3; ++ks) {
        if constexpr (USE_WS)
          wb[ks] = *(const bf16x8*)(qwb + (frow + l16) * 96 + 32 * ks + 8 * lq);
        else
          wb[ks] = cvt8(qkv_w + (frow + l16) * 96 + 32 * ks + 8 * lq);
      }
      const float4 qb4 = *(const float4*)(qkv_b + frow + 4 * lq);
#pragma unroll
      for (int mt = 0; mt < 4; ++mt) {
        f32x4 acc = {qb4.x, qb4.y, qb4.z, qb4.w};
#pragma unroll
        for (int ks = 0; ks < 3; ++ks) acc = mfma32(wb[ks], XV(mt, ks), acc);
#pragma unroll
        for (int r = 0; r < 4; ++r) qv4[mt][r] = (__bf16)(acc[r] * 0.25f);
      }
    }

    // V phase: D = X * Wv^T + vb; D-frag mt=a IS the O^T A-frag chunk a
    bf16x4 vb4[4];
    {
      const int frow = (2 * HEADS + h) * 16;
      bf16x8 wb[3];
#pragma unroll
      for (int ks = 0; ks < 3; ++ks) {
        if constexpr (USE_WS)
          wb[ks] = *(const bf16x8*)(qwb + (frow + l16) * 96 + 32 * ks + 8 * lq);
        else
          wb[ks] = cvt8(qkv_w + (frow + l16) * 96 + 32 * ks + 8 * lq);
      }
      const float vb = qkv_b[frow + l16];
#pragma unroll
      for (int mt = 0; mt < 4; ++mt) {
        f32x4 acc = {vb, vb, vb, vb};
#pragma unroll
        for (int ks = 0; ks < 3; ++ks) acc = mfma32(XV(mt, ks), wb[ks], acc);
#pragma unroll
        for (int r = 0; r < 4; ++r) vb4[mt][r] = (__bf16)acc[r];
      }
    }

    // proj weight chunks for this head: B[col=16c+l16][k=16h+4lq+e]
    bf16x4 wpch[6];
#pragma unroll
    for (int c = 0; c < 6; ++c) {
      if constexpr (USE_WS)
        wpch[c] = *(const bf16x4*)(pwb + (16 * c + l16) * 96 + 16 * h + 4 * lq);
      else
        wpch[c] = cvt4(proj_w + (16 * c + l16) * 96 + 16 * h + 4 * lq);
    }

    const float4* bias4 = (const float4*)(ws + WS_BIAS) + (h << 10);
#pragma unroll
    for (int bq = 0; bq < 4; ++bq) {
      f32x4 s[4];
      if constexpr (USE_WS) {
#pragma unroll
        for (int a = 0; a < 4; ++a)
          s[a] = __builtin_bit_cast(f32x4, bias4[(bq * 4 + a) * 64 + lane]);
      } else {
#pragma unroll
        for (int a = 0; a < 4; ++a) {
          const i32x4 idx =
              *(const i32x4*)(rpi + (16 * bq + l16) * 64 + 16 * a + 4 * lq);
#pragma unroll
          for (int r = 0; r < 4; ++r) s[a][r] = rpb[idx[r] * HEADS + h];
        }
      }

      // QK^T: S^T = K * Q^T with bias as C-init
#pragma unroll
      for (int a = 0; a < 4; ++a) s[a] = mfma16k(kb[a], qv4[bq], s[a]);

      // unnormalized softmax (|logits|<<1 -> exp direct); tsum from the
      // bf16-rounded P so numerator/denominator match (r9 lesson)
      float tp[4];
      bf16x4 pa[4];
#pragma unroll
      for (int a = 0; a < 4; ++a) {
        float t0 = 0.f;
#pragma unroll
        for (int r = 0; r < 4; ++r) {
          const __bf16 pe = (__bf16)__expf(s[a][r]);
          pa[a][r] = pe;
          t0 += (float)pe;
        }
        tp[a] = t0;
      }
      float tsum = (tp[0] + tp[1]) + (tp[2] + tp[3]);
      tsum += __shfl_xor(tsum, 16);
      tsum += __shfl_xor(tsum, 32);  // rcp latency hides under O^T below

      // O^T = sum_a V^T_chunk[a] * P^T_chunk[a]: D col=l16=q, row=4lq+r=feat
      f32x4 ot = {0.f, 0.f, 0.f, 0.f};
#pragma unroll
      for (int a = 0; a < 4; ++a) ot = mfma16k(vb4[a], pa[a], ot);

      const float rv = 1.0f / tsum;  // per-q (lane-local), same for all r
      bf16x4 oat;
#pragma unroll
      for (int r = 0; r < 4; ++r) oat[r] = (__bf16)(ot[r] * rv);

      // proj: pacc[bq][c] += oat * Wp_chunk(h,c) — head-sum via MFMA C
#pragma unroll
      for (int c = 0; c < 6; ++c)
        pacc[bq][c] = mfma16k(oat, wpch[c], pacc[bq][c]);
    }
  }
#undef XV

  // ---- final store: D row=4lq+r -> token 16bq+4lq+r, col=l16 -> 16c+l16 ----
  float* outw = out + (size_t)b * (NTOK * DIM);
#pragma unroll
  for (int bq = 0; bq < 4; ++bq)
#pragma unroll
    for (int c = 0; c < 6; ++c)
#pragma unroll
      for (int r = 0; r < 4; ++r)
        outw[(16 * bq + 4 * lq + r) * 96 + 16 * c + l16] = pacc[bq][c][r];
}

extern "C" void kernel_launch(void* const* d_in, const int* in_sizes, int n_in,
                              void* d_out, int out_size, void* d_ws, size_t ws_size,
                              hipStream_t stream) {
  const float* x      = (const float*)d_in[0];
  const int*   rpi    = (const int*)d_in[1];
  const float* qkv_w  = (const float*)d_in[2];
  const float* qkv_b  = (const float*)d_in[3];
  const float* proj_w = (const float*)d_in[4];
  const float* proj_b = (const float*)d_in[5];
  const float* rpb    = (const float*)d_in[6];
  float* out = (float*)d_out;

  if (ws_size >= (size_t)WS_TOTAL) {
    prep_kernel<<<240, 256, 0, stream>>>(qkv_w, proj_w, rpb, rpi, (char*)d_ws);
    win_attn<true><<<NWIN, 64, 0, stream>>>(x, rpi, qkv_w, qkv_b, proj_w,
                                            proj_b, rpb, (const char*)d_ws,
                                            out);
  } else {
    win_attn<false><<<NWIN, 64, 0, stream>>>(x, rpi, qkv_w, qkv_b, proj_w,
                                             proj_b, rpb, (const char*)d_ws,
                                             out);
  }
}

// Round 20
// 82.169 us; speedup vs baseline: 2.3829x; 1.0524x over previous
//
#include <hip/hip_runtime.h>

#define NWIN 4096
#define DIM 96
#define HEADS 6
#define NTOK 64
#define WPB 4  // windows per block; grid = NWIN/WPB = 1024

typedef __bf16 bf16x8 __attribute__((ext_vector_type(8)));
typedef __bf16 bf16x4 __attribute__((ext_vector_type(4)));
typedef short  s16x4  __attribute__((ext_vector_type(4)));
typedef float  f32x4  __attribute__((ext_vector_type(4)));

// d_ws layout
#define WS_QKVW 0                   // 288*96 bf16 = 55296 B
#define WS_PROJW 55296              // 96*96 bf16  = 18432 B
#define WS_BIAS 73728               // 6*16*64 float4 = 98304 B (frag-ordered)
#define WS_TOTAL 172032

__device__ __forceinline__ f32x4 mfma32(bf16x8 a, bf16x8 b, f32x4 c) {
  return __builtin_amdgcn_mfma_f32_16x16x32_bf16(a, b, c, 0, 0, 0);
}
// K=16 MFMA. Fragment alignment facts (verified r7-r19):
//  * A/B fragment lane(l16,lq) holds row/col=l16, k=4*lq+e  — identical to
//    the W*X^T D-fragment (row=4lq+r, col=l16), so K,Q stay in registers.
//  * QK^T output s[a] = S[q=l16][kv=16a+4lq+r] — IS the PV A-frag chunk a.
//  * V-phase D-frag for mt=a IS the PV B-frag chunk a.
__device__ __forceinline__ f32x4 mfma16k(bf16x4 a, bf16x4 b, f32x4 c) {
  return __builtin_amdgcn_mfma_f32_16x16x16bf16_1k(
      __builtin_bit_cast(s16x4, a), __builtin_bit_cast(s16x4, b), c, 0, 0, 0);
}

__device__ __forceinline__ bf16x8 cvt8(const float* p) {
  const float4* q = (const float4*)p;
  float4 a = q[0];
  float4 b = q[1];
  bf16x8 r;
  r[0] = (__bf16)a.x; r[1] = (__bf16)a.y; r[2] = (__bf16)a.z; r[3] = (__bf16)a.w;
  r[4] = (__bf16)b.x; r[5] = (__bf16)b.y; r[6] = (__bf16)b.z; r[7] = (__bf16)b.w;
  return r;
}

// Pre-pass: weights -> bf16; bias gathered into MFMA-fragment order:
// bias[((h*16 + bq*4 + a)*64 + lane)*4 + r] = rpb[rpi[qrow*64+kcol]*6+h]
// with qrow = 16*bq + (lane&15), kcol = 16*a + 4*(lane>>4) + r.
// (Replay-stable across r2/4/6/8/9/14/15/16/19.)
__global__ void prep_kernel(const float* __restrict__ qkv_w,
                            const float* __restrict__ proj_w,
                            const float* __restrict__ rpb,
                            const int* __restrict__ rpi,
                            char* __restrict__ ws) {
  int i = blockIdx.x * blockDim.x + threadIdx.x;
  __bf16* qw = (__bf16*)(ws + WS_QKVW);
  __bf16* pw = (__bf16*)(ws + WS_PROJW);
  float* bias = (float*)(ws + WS_BIAS);
  if (i < 288 * 96) qw[i] = (__bf16)qkv_w[i];
  int j = i - 288 * 96;
  if (j >= 0 && j < 96 * 96) pw[j] = (__bf16)proj_w[j];
  int t = i - (288 * 96 + 96 * 96);
  if (t >= 0 && t < HEADS * 16 * 64 * 4) {
    int r = t & 3;
    int lane = (t >> 2) & 63;
    int ba = (t >> 8) & 15;
    int h = t >> 12;
    int bq = ba >> 2, a = ba & 3;
    int l16 = lane & 15, lq = lane >> 4;
    int qrow = 16 * bq + l16;
    int kcol = 16 * a + 4 * lq + r;
    bias[t] = rpb[rpi[qrow * 64 + kcol] * HEADS + h];
  }
}

// r20: r15's proven body (2-wave blocks, 3 heads/wave, 72 VGPR clean) +
// WPB=4 windows per block + REGISTER PREFETCH of window i+1's x (48 regs,
// live only across proj — intra-iteration). This is r12/r13's idea run
// CLEAN: those spilled because launch_bounds under-budgeted the live set
// (512/min_waves is a HARD cap; r19 disproved any separate "64-arch cliff"
// — 112 VGPR ran spill-free at (64,2)). Here: (128,2) -> 256-reg budget vs
// ~125 peak. Rationale: 8 clean structures plateau at 82-87us with block
// lifetime ~8us vs ~2K cycles of issue work; the head of each window's
// serial chain is the ~1-2us x fetch — hide it under the previous window's
// proj. LDS: xfrag[2]+ao = 37888 B. Barriers/iter: B_ao, B_x (hazards:
// xfrag[b] written iter i after B_ao > its last read iter i-1 frontend;
// ao written iter i+1 attention after B_x > proj(i) reads).
template <bool USE_WS>
__global__ __launch_bounds__(128, 2) void win_attn(
    const float* __restrict__ x,
    const int* __restrict__ rpi,
    const float* __restrict__ qkv_w,
    const float* __restrict__ qkv_b,
    const float* __restrict__ proj_w,
    const float* __restrict__ proj_b,
    const float* __restrict__ rpb,
    const char* __restrict__ ws,
    float* __restrict__ out) {
  __shared__ __align__(16) __bf16 xfrag[2][6144];  // 12 frags * 512 bf16 each
  __shared__ __align__(16) __bf16 ao[64 * 104];    // 13312 B

  const int tid = (int)threadIdx.x;
  const int wv = tid >> 6;  // 0..1
  const int lane = tid & 63;
  const int l16 = lane & 15;
  const int lq = lane >> 4;
  const int base = (int)blockIdx.x * WPB;

  const __bf16* qwb = (const __bf16*)(ws + WS_QKVW);
  const __bf16* pwb = (const __bf16*)(ws + WS_PROJW);

  // ---- prologue: stage window base+0 (wave wv does frags 6wv..6wv+5) ----
  {
    const float* xw = x + (size_t)base * (NTOK * DIM);
#pragma unroll
    for (int ff = 0; ff < 6; ++ff) {
      const int mt = 2 * wv + ff / 3;  // compile-time ff/3
      const int ks = ff % 3;
      const int f = 6 * wv + ff;
      bf16x8 v = cvt8(xw + (16 * mt + l16) * DIM + 32 * ks + 8 * lq);
      *(bf16x8*)(xfrag[0] + (f * 64 + lane) * 8) = v;
    }
  }
  __syncthreads();

#pragma unroll 1
  for (int i = 0; i < WPB; ++i) {
    const __bf16* xf = xfrag[i & 1];
    const int b = base + i;

#define XV(mt, ks) (*(const bf16x8*)(xf + (((mt) * 3 + (ks)) * 64 + lane) * 8))

    // ---- 3 heads sequentially per wave; NO unroll (register discipline) ----
#pragma unroll 1
    for (int hh = 0; hh < 3; ++hh) {
      const int h = wv + 2 * hh;

      // K phase: D = Wk * X^T + kb (bias C-init); D-frag stays in regs
      bf16x4 kb[4];
      {
        const int frow = (HEADS + h) * 16;
        bf16x8 wb[3];
#pragma unroll
        for (int ks = 0; ks < 3; ++ks) {
          if constexpr (USE_WS)
            wb[ks] =
                *(const bf16x8*)(qwb + (frow + l16) * 96 + 32 * ks + 8 * lq);
          else
            wb[ks] = cvt8(qkv_w + (frow + l16) * 96 + 32 * ks + 8 * lq);
        }
        const float4 kb4 = *(const float4*)(qkv_b + frow + 4 * lq);
#pragma unroll
        for (int mt = 0; mt < 4; ++mt) {
          f32x4 acc = {kb4.x, kb4.y, kb4.z, kb4.w};
#pragma unroll
          for (int ks = 0; ks < 3; ++ks) acc = mfma32(wb[ks], XV(mt, ks), acc);
#pragma unroll
          for (int r = 0; r < 4; ++r) kb[mt][r] = (__bf16)acc[r];
        }
      }

      // Q phase: D = (Wq * X^T + qb) * 0.25; registers only
      bf16x4 qv4[4];
      {
        const int frow = h * 16;
        bf16x8 wb[3];
#pragma unroll
        for (int ks = 0; ks < 3; ++ks) {
          if constexpr (USE_WS)
            wb[ks] =
                *(const bf16x8*)(qwb + (frow + l16) * 96 + 32 * ks + 8 * lq);
          else
            wb[ks] = cvt8(qkv_w + (frow + l16) * 96 + 32 * ks + 8 * lq);
        }
        const float4 qb4 = *(const float4*)(qkv_b + frow + 4 * lq);
#pragma unroll
        for (int mt = 0; mt < 4; ++mt) {
          f32x4 acc = {qb4.x, qb4.y, qb4.z, qb4.w};
#pragma unroll
          for (int ks = 0; ks < 3; ++ks) acc = mfma32(wb[ks], XV(mt, ks), acc);
#pragma unroll
          for (int r = 0; r < 4; ++r) qv4[mt][r] = (__bf16)(acc[r] * 0.25f);
        }
      }

      // V phase: D = X * Wv^T + vb; D-frag mt=a IS the PV B-frag chunk a
      bf16x4 vb4[4];
      {
        const int frow = (2 * HEADS + h) * 16;
        bf16x8 wb[3];
#pragma unroll
        for (int ks = 0; ks < 3; ++ks) {
          if constexpr (USE_WS)
            wb[ks] =
                *(const bf16x8*)(qwb + (frow + l16) * 96 + 32 * ks + 8 * lq);
          else
            wb[ks] = cvt8(qkv_w + (frow + l16) * 96 + 32 * ks + 8 * lq);
        }
        const float vb = qkv_b[frow + l16];
#pragma unroll
        for (int mt = 0; mt < 4; ++mt) {
          f32x4 acc = {vb, vb, vb, vb};
#pragma unroll
          for (int ks = 0; ks < 3; ++ks) acc = mfma32(XV(mt, ks), wb[ks], acc);
#pragma unroll
          for (int r = 0; r < 4; ++r) vb4[mt][r] = (__bf16)acc[r];
        }
      }

      // attention per q-tile: pure register dataflow
      const float4* bias4 = (const float4*)(ws + WS_BIAS) + (h << 10);
#pragma unroll
      for (int bq = 0; bq < 4; ++bq) {
        f32x4 s[4];
        if constexpr (USE_WS) {
#pragma unroll
          for (int a = 0; a < 4; ++a)
            s[a] = __builtin_bit_cast(f32x4, bias4[(bq * 4 + a) * 64 + lane]);
        } else {
#pragma unroll
          for (int a = 0; a < 4; ++a)
#pragma unroll
            for (int r = 0; r < 4; ++r)
              s[a][r] = rpb[rpi[(16 * bq + l16) * 64 + 16 * a + 4 * lq + r] *
                                HEADS + h];
        }

        // QK^T: S^T = K * Q^T with bias as C-init
#pragma unroll
        for (int a = 0; a < 4; ++a) s[a] = mfma16k(kb[a], qv4[bq], s[a]);

        // unnormalized softmax (|logits|<<1 -> exp direct); tsum from the
        // bf16-rounded P so numerator/denominator match (r9 lesson)
        float tp[4];
        bf16x4 pa[4];
#pragma unroll
        for (int a = 0; a < 4; ++a) {
          float t0 = 0.f;
#pragma unroll
          for (int r = 0; r < 4; ++r) {
            const __bf16 pe = (__bf16)__expf(s[a][r]);
            pa[a][r] = pe;
            t0 += (float)pe;
          }
          tp[a] = t0;
        }
        float tsum = (tp[0] + tp[1]) + (tp[2] + tp[3]);
        tsum += __shfl_xor(tsum, 16);
        tsum += __shfl_xor(tsum, 32);  // rcp latency hides under PV

        // PV: O_tile = sum_a P_chunk[a] * V_chunk[a], all in registers
        f32x4 oacc = {0.f, 0.f, 0.f, 0.f};
#pragma unroll
        for (int a = 0; a < 4; ++a) oacc = mfma16k(pa[a], vb4[a], oacc);

        const float rv = 1.0f / tsum;  // normalize after PV (linearity)
#pragma unroll
        for (int r = 0; r < 4; ++r)
          ao[(16 * bq + 4 * lq + r) * 104 + 16 * h + l16] =
              (__bf16)(oacc[r] * rv);
      }
    }
#undef XV
    __syncthreads();  // B_ao: ao complete; xf reads done

    // ---- issue next window's x loads (48 regs; latency hides under proj) --
    float4 xr[12];
    if (i + 1 < WPB) {
      const float* xw = x + (size_t)(b + 1) * (NTOK * DIM);
#pragma unroll
      for (int ff = 0; ff < 6; ++ff) {
        const int mt = 2 * wv + ff / 3;
        const int ks = ff % 3;
        const float4* p =
            (const float4*)(xw + (16 * mt + l16) * DIM + 32 * ks + 8 * lq);
        xr[2 * ff] = p[0];
        xr[2 * ff + 1] = p[1];
      }
    }

    // ---- proj: 3 column-tiles per wave (c = wv, wv+2, wv+4) ----
    float* outw = out + (size_t)b * (NTOK * DIM);
#pragma unroll 1
    for (int cc = 0; cc < 3; ++cc) {
      const int c = wv + 2 * cc;
      bf16x8 wpb[3];
#pragma unroll
      for (int ks = 0; ks < 3; ++ks) {
        if constexpr (USE_WS)
          wpb[ks] =
              *(const bf16x8*)(pwb + (16 * c + l16) * 96 + 32 * ks + 8 * lq);
        else
          wpb[ks] = cvt8(proj_w + (16 * c + l16) * 96 + 32 * ks + 8 * lq);
      }
      const float pb2 = proj_b[16 * c + l16];
#pragma unroll
      for (int mt = 0; mt < 4; ++mt) {
        f32x4 acc = {pb2, pb2, pb2, pb2};
#pragma unroll
        for (int ks = 0; ks < 3; ++ks) {
          bf16x8 aa =
              *(const bf16x8*)(ao + (16 * mt + l16) * 104 + 32 * ks + 8 * lq);
          acc = mfma32(aa, wpb[ks], acc);
        }
#pragma unroll
        for (int r = 0; r < 4; ++r)
          outw[(16 * mt + 4 * lq + r) * 96 + 16 * c + l16] = acc[r];
      }
    }

    // ---- convert+store prefetched x into the other buffer ----
    if (i + 1 < WPB) {
#pragma unroll
      for (int ff = 0; ff < 6; ++ff) {
        const int f = 6 * wv + ff;
        const float4 a = xr[2 * ff], c4 = xr[2 * ff + 1];
        bf16x8 v;
        v[0] = (__bf16)a.x;  v[1] = (__bf16)a.y;
        v[2] = (__bf16)a.z;  v[3] = (__bf16)a.w;
        v[4] = (__bf16)c4.x; v[5] = (__bf16)c4.y;
        v[6] = (__bf16)c4.z; v[7] = (__bf16)c4.w;
        *(bf16x8*)(xfrag[(i + 1) & 1] + (f * 64 + lane) * 8) = v;
      }
      __syncthreads();  // B_x: next xfrag visible; proj done reading ao
    }
  }
}

extern "C" void kernel_launch(void* const* d_in, const int* in_sizes, int n_in,
                              void* d_out, int out_size, void* d_ws, size_t ws_size,
                              hipStream_t stream) {
  const float* x      = (const float*)d_in[0];
  const int*   rpi    = (const int*)d_in[1];
  const float* qkv_w  = (const float*)d_in[2];
  const float* qkv_b  = (const float*)d_in[3];
  const float* proj_w = (const float*)d_in[4];
  const float* proj_b = (const float*)d_in[5];
  const float* rpb    = (const float*)d_in[6];
  float* out = (float*)d_out;

  if (ws_size >= (size_t)WS_TOTAL) {
    prep_kernel<<<240, 256, 0, stream>>>(qkv_w, proj_w, rpb, rpi, (char*)d_ws);
    win_attn<true><<<NWIN / WPB, 128, 0, stream>>>(
        x, rpi, qkv_w, qkv_b, proj_w, proj_b, rpb, (const char*)d_ws, out);
  } else {
    win_attn<false><<<NWIN / WPB, 128, 0, stream>>>(
        x, rpi, qkv_w, qkv_b, proj_w, proj_b, rpb, (const char*)d_ws, out);
  }
}

// Round 21
// 75.936 us; speedup vs baseline: 2.5785x; 1.0821x over previous
//
#include <hip/hip_runtime.h>

#define NWIN 4096
#define DIM 96
#define HEADS 6
#define NTOK 64
#define QS 0.36067376022224085f  // 0.25 * log2(e): folded into q-weights/bias

typedef __bf16 bf16x8 __attribute__((ext_vector_type(8)));
typedef __bf16 bf16x4 __attribute__((ext_vector_type(4)));
typedef short  s16x4  __attribute__((ext_vector_type(4)));
typedef float  f32x4  __attribute__((ext_vector_type(4)));

#if __has_builtin(__builtin_amdgcn_exp2f)
#define EXP2(x) __builtin_amdgcn_exp2f(x)   // bare v_exp_f32, no libm wrapper
#else
#define EXP2(x) exp2f(x)
#endif
#if __has_builtin(__builtin_amdgcn_rcpf)
#define RCP(x) __builtin_amdgcn_rcpf(x)     // bare v_rcp_f32 (2^-22 rel err)
#else
#define RCP(x) (1.0f / (x))
#endif

// d_ws layout
#define WS_QKVW 0                   // 288*96 bf16 = 55296 B (q rows prescaled)
#define WS_PROJW 55296              // 96*96 bf16  = 18432 B
#define WS_BIAS 73728               // 6*16*64 float4 = 98304 B (x log2e)
#define WS_TOTAL 172032

__device__ __forceinline__ f32x4 mfma32(bf16x8 a, bf16x8 b, f32x4 c) {
  return __builtin_amdgcn_mfma_f32_16x16x32_bf16(a, b, c, 0, 0, 0);
}
// K=16 MFMA. Fragment alignment facts (verified r7-r20):
//  * A/B fragment lane(l16,lq) holds row/col=l16, k=4*lq+e  — identical to
//    the W*X^T D-fragment (row=4lq+r, col=l16), so K,Q stay in registers.
//  * QK^T output s[a] = S[q=l16][kv=16a+4lq+r] — IS the PV A-frag chunk a.
//  * V-phase D-frag for mt=a IS the PV B-frag chunk a.
__device__ __forceinline__ f32x4 mfma16k(bf16x4 a, bf16x4 b, f32x4 c) {
  return __builtin_amdgcn_mfma_f32_16x16x16bf16_1k(
      __builtin_bit_cast(s16x4, a), __builtin_bit_cast(s16x4, b), c, 0, 0, 0);
}

__device__ __forceinline__ bf16x8 cvt8(const float* p) {
  const float4* q = (const float4*)p;
  float4 a = q[0];
  float4 b = q[1];
  bf16x8 r;
  r[0] = (__bf16)a.x; r[1] = (__bf16)a.y; r[2] = (__bf16)a.z; r[3] = (__bf16)a.w;
  r[4] = (__bf16)b.x; r[5] = (__bf16)b.y; r[6] = (__bf16)b.z; r[7] = (__bf16)b.w;
  return r;
}

// Pre-pass: weights -> bf16 (q rows x QS so QK logits arrive pre-scaled for
// exp2); bias gathered into MFMA-fragment order and x log2(e):
// bias[((h*16 + bq*4 + a)*64 + lane)*4 + r] = log2e * rpb[rpi[qrow*64+kcol]*6+h]
// (Replay-stable staging across r2/4/6/8/9/14/15/16/19/20.)
__global__ void prep_kernel(const float* __restrict__ qkv_w,
                            const float* __restrict__ proj_w,
                            const float* __restrict__ rpb,
                            const int* __restrict__ rpi,
                            char* __restrict__ ws) {
  int i = blockIdx.x * blockDim.x + threadIdx.x;
  __bf16* qw = (__bf16*)(ws + WS_QKVW);
  __bf16* pw = (__bf16*)(ws + WS_PROJW);
  float* bias = (float*)(ws + WS_BIAS);
  if (i < 288 * 96) {
    float v = qkv_w[i];
    if (i < 96 * 96) v *= QS;  // q feature rows: fold 0.25*log2e
    qw[i] = (__bf16)v;
  }
  int j = i - 288 * 96;
  if (j >= 0 && j < 96 * 96) pw[j] = (__bf16)proj_w[j];
  int t = i - (288 * 96 + 96 * 96);
  if (t >= 0 && t < HEADS * 16 * 64 * 4) {
    int r = t & 3;
    int lane = (t >> 2) & 63;
    int ba = (t >> 8) & 15;
    int h = t >> 12;
    int bq = ba >> 2, a = ba & 3;
    int l16 = lane & 15, lq = lane >> 4;
    int qrow = 16 * bq + l16;
    int kcol = 16 * a + 4 * lq + r;
    bias[t] = 1.4426950408889634f * rpb[rpi[qrow * 64 + kcol] * HEADS + h];
  }
}

// r21: r15/r16 structure (proven clean: ~72-80 VGPR, no spill, 25600 B LDS,
// 2 barriers, 2-wave blocks, 3 heads/wave) with the VALU diet done RIGHT:
// r16's libm exp2f ADDED range-fixup code (VALUBusy 40->48%); this round
// uses __builtin_amdgcn_exp2f (bare v_exp_f32, log2e prep-folded) and
// __builtin_amdgcn_rcpf (bare v_rcp_f32). setprio removed (confound).
// Issue-port audit: VALU ~32% + MFMA ~13% + VMEM/SALU on shared SIMD ports
// -> possibly issue-bound; softmax is the fattest VALU block. This is the
// clean A/B of that hypothesis.
template <bool USE_WS>
__global__ __launch_bounds__(128, 4) void win_attn(
    const float* __restrict__ x,
    const int* __restrict__ rpi,
    const float* __restrict__ qkv_w,
    const float* __restrict__ qkv_b,
    const float* __restrict__ proj_w,
    const float* __restrict__ proj_b,
    const float* __restrict__ rpb,
    const char* __restrict__ ws,
    float* __restrict__ out) {
  __shared__ __align__(16) __bf16 xfrag[6144];   // 12 frags * 512 bf16
  __shared__ __align__(16) __bf16 ao[64 * 104];  // 13312 B

  const int tid = (int)threadIdx.x;
  const int wv = tid >> 6;  // 0..1
  const int lane = tid & 63;
  const int l16 = lane & 15;
  const int lq = lane >> 4;
  const int b = (int)blockIdx.x;

  const float* xw = x + (size_t)b * (NTOK * DIM);
  const __bf16* qwb = (const __bf16*)(ws + WS_QKVW);
  const __bf16* pwb = (const __bf16*)(ws + WS_PROJW);

  // ---- stage x fragments (wave wv does frags 6wv..6wv+5; mt,ks static) ----
#pragma unroll
  for (int ff = 0; ff < 6; ++ff) {
    const int mt = 2 * wv + ff / 3;
    const int ks = ff % 3;
    const int f = 6 * wv + ff;
    bf16x8 v = cvt8(xw + (16 * mt + l16) * DIM + 32 * ks + 8 * lq);
    *(bf16x8*)(xfrag + (f * 64 + lane) * 8) = v;
  }
  __syncthreads();

#define XV(mt, ks) (*(const bf16x8*)(xfrag + (((mt) * 3 + (ks)) * 64 + lane) * 8))

  // ---- 3 heads sequentially per wave; NO unroll (register discipline) ----
#pragma unroll 1
  for (int hh = 0; hh < 3; ++hh) {
    const int h = wv + 2 * hh;

    // K phase: D = Wk * X^T + kb (bias as C-init); D-frag stays in regs
    bf16x4 kb[4];
    {
      const int frow = (HEADS + h) * 16;
      bf16x8 wb[3];
#pragma unroll
      for (int ks = 0; ks < 3; ++ks) {
        if constexpr (USE_WS)
          wb[ks] = *(const bf16x8*)(qwb + (frow + l16) * 96 + 32 * ks + 8 * lq);
        else
          wb[ks] = cvt8(qkv_w + (frow + l16) * 96 + 32 * ks + 8 * lq);
      }
      const float4 kb4 = *(const float4*)(qkv_b + frow + 4 * lq);
#pragma unroll
      for (int mt = 0; mt < 4; ++mt) {
        f32x4 acc = {kb4.x, kb4.y, kb4.z, kb4.w};
#pragma unroll
        for (int ks = 0; ks < 3; ++ks) acc = mfma32(wb[ks], XV(mt, ks), acc);
#pragma unroll
        for (int r = 0; r < 4; ++r) kb[mt][r] = (__bf16)acc[r];
      }
    }

    // Q phase: D = Wq' * X^T + qb' (weights prescaled by QS in prep)
    bf16x4 qv4[4];
    {
      const int frow = h * 16;
      bf16x8 wb[3];
#pragma unroll
      for (int ks = 0; ks < 3; ++ks) {
        if constexpr (USE_WS)
          wb[ks] = *(const bf16x8*)(qwb + (frow + l16) * 96 + 32 * ks + 8 * lq);
        else
          wb[ks] = cvt8(qkv_w + (frow + l16) * 96 + 32 * ks + 8 * lq);
      }
      const float4 qb4 = *(const float4*)(qkv_b + frow + 4 * lq);
#pragma unroll
      for (int mt = 0; mt < 4; ++mt) {
        f32x4 acc;
        if constexpr (USE_WS) {
          acc[0] = qb4.x * QS; acc[1] = qb4.y * QS;
          acc[2] = qb4.z * QS; acc[3] = qb4.w * QS;
        } else {
          acc[0] = qb4.x; acc[1] = qb4.y; acc[2] = qb4.z; acc[3] = qb4.w;
        }
#pragma unroll
        for (int ks = 0; ks < 3; ++ks) acc = mfma32(wb[ks], XV(mt, ks), acc);
#pragma unroll
        for (int r = 0; r < 4; ++r) {
          if constexpr (USE_WS)
            qv4[mt][r] = (__bf16)acc[r];          // scale already in weights
          else
            qv4[mt][r] = (__bf16)(acc[r] * QS);   // fallback: scale here
        }
      }
    }

    // V phase: D = X * Wv^T + vb (col-bias broadcast C-init)
    bf16x4 vb4[4];
    {
      const int frow = (2 * HEADS + h) * 16;
      bf16x8 wb[3];
#pragma unroll
      for (int ks = 0; ks < 3; ++ks) {
        if constexpr (USE_WS)
          wb[ks] = *(const bf16x8*)(qwb + (frow + l16) * 96 + 32 * ks + 8 * lq);
        else
          wb[ks] = cvt8(qkv_w + (frow + l16) * 96 + 32 * ks + 8 * lq);
      }
      const float vb = qkv_b[frow + l16];
#pragma unroll
      for (int mt = 0; mt < 4; ++mt) {
        f32x4 acc = {vb, vb, vb, vb};
#pragma unroll
        for (int ks = 0; ks < 3; ++ks) acc = mfma32(XV(mt, ks), wb[ks], acc);
#pragma unroll
        for (int r = 0; r < 4; ++r) vb4[mt][r] = (__bf16)acc[r];
      }
    }

    // attention per q-tile: pure register dataflow
    const float4* bias4 = (const float4*)(ws + WS_BIAS) + (h << 10);
#pragma unroll
    for (int bq = 0; bq < 4; ++bq) {
      f32x4 s[4];
      if constexpr (USE_WS) {
#pragma unroll
        for (int a = 0; a < 4; ++a)
          s[a] = __builtin_bit_cast(f32x4, bias4[(bq * 4 + a) * 64 + lane]);
      } else {
#pragma unroll
        for (int a = 0; a < 4; ++a)
#pragma unroll
          for (int r = 0; r < 4; ++r)
            s[a][r] = 1.4426950408889634f *
                      rpb[rpi[(16 * bq + l16) * 64 + 16 * a + 4 * lq + r] *
                              HEADS + h];
      }

      // QK^T: S^T = K * Q^T with (log2e-scaled) bias as C-init
#pragma unroll
      for (int a = 0; a < 4; ++a) s[a] = mfma16k(kb[a], qv4[bq], s[a]);

      // softmax: logits pre-scaled by log2e -> bare v_exp_f32.
      // tsum from the bf16-rounded P so numerator/denominator match (r9).
      float tp[4];
      bf16x4 pa[4];
#pragma unroll
      for (int a = 0; a < 4; ++a) {
        float t0 = 0.f;
#pragma unroll
        for (int r = 0; r < 4; ++r) {
          const __bf16 pe = (__bf16)EXP2(s[a][r]);
          pa[a][r] = pe;
          t0 += (float)pe;
        }
        tp[a] = t0;
      }
      float tsum = (tp[0] + tp[1]) + (tp[2] + tp[3]);
      tsum += __shfl_xor(tsum, 16);
      tsum += __shfl_xor(tsum, 32);  // rcp latency hides under PV

      // PV: O_tile = sum_a P_chunk[a] * V_chunk[a], all in registers
      f32x4 oacc = {0.f, 0.f, 0.f, 0.f};
#pragma unroll
      for (int a = 0; a < 4; ++a) oacc = mfma16k(pa[a], vb4[a], oacc);

      const float rv = RCP(tsum);  // normalize after PV (linearity)
#pragma unroll
      for (int r = 0; r < 4; ++r)
        ao[(16 * bq + 4 * lq + r) * 104 + 16 * h + l16] =
            (__bf16)(oacc[r] * rv);
    }
  }
#undef XV
  __syncthreads();  // ao complete (xfrag disjoint: no overlay hazard)

  // ---- proj: 3 column-tiles per wave (c = wv, wv+2, wv+4); no hoisting ----
  float* outw = out + (size_t)b * (NTOK * DIM);
#pragma unroll 1
  for (int cc = 0; cc < 3; ++cc) {
    const int c = wv + 2 * cc;
    bf16x8 wpb[3];
#pragma unroll
    for (int ks = 0; ks < 3; ++ks) {
      if constexpr (USE_WS)
        wpb[ks] = *(const bf16x8*)(pwb + (16 * c + l16) * 96 + 32 * ks + 8 * lq);
      else
        wpb[ks] = cvt8(proj_w + (16 * c + l16) * 96 + 32 * ks + 8 * lq);
    }
    const float pb2 = proj_b[16 * c + l16];
#pragma unroll
    for (int mt = 0; mt < 4; ++mt) {
      f32x4 acc = {pb2, pb2, pb2, pb2};  // bias C-init (per-col broadcast)
#pragma unroll
      for (int ks = 0; ks < 3; ++ks) {
        bf16x8 aa =
            *(const bf16x8*)(ao + (16 * mt + l16) * 104 + 32 * ks + 8 * lq);
        acc = mfma32(aa, wpb[ks], acc);
      }
#pragma unroll
      for (int r = 0; r < 4; ++r)
        outw[(16 * mt + 4 * lq + r) * 96 + 16 * c + l16] = acc[r];
    }
  }
}

extern "C" void kernel_launch(void* const* d_in, const int* in_sizes, int n_in,
                              void* d_out, int out_size, void* d_ws, size_t ws_size,
                              hipStream_t stream) {
  const float* x      = (const float*)d_in[0];
  const int*   rpi    = (const int*)d_in[1];
  const float* qkv_w  = (const float*)d_in[2];
  const float* qkv_b  = (const float*)d_in[3];
  const float* proj_w = (const float*)d_in[4];
  const float* proj_b = (const float*)d_in[5];
  const float* rpb    = (const float*)d_in[6];
  float* out = (float*)d_out;

  if (ws_size >= (size_t)WS_TOTAL) {
    prep_kernel<<<240, 256, 0, stream>>>(qkv_w, proj_w, rpb, rpi, (char*)d_ws);
    win_attn<true><<<NWIN, 128, 0, stream>>>(x, rpi, qkv_w, qkv_b, proj_w,
                                             proj_b, rpb, (const char*)d_ws,
                                             out);
  } else {
    win_attn<false><<<NWIN, 128, 0, stream>>>(x, rpi, qkv_w, qkv_b, proj_w,
                                              proj_b, rpb, (const char*)d_ws,
                                              out);
  }
}

// Round 22
// 73.914 us; speedup vs baseline: 2.6490x; 1.0273x over previous
//
#include <hip/hip_runtime.h>

#define NWIN 4096
#define DIM 96
#define HEADS 6
#define NTOK 64
#define QS 0.36067376022224085f  // 0.25 * log2(e): folded into q-weights/bias

typedef __bf16 bf16x8 __attribute__((ext_vector_type(8)));
typedef __bf16 bf16x4 __attribute__((ext_vector_type(4)));
typedef short  s16x4  __attribute__((ext_vector_type(4)));
typedef float  f32x4  __attribute__((ext_vector_type(4)));

#if __has_builtin(__builtin_amdgcn_exp2f)
#define EXP2(x) __builtin_amdgcn_exp2f(x)   // bare v_exp_f32, no libm wrapper
#else
#define EXP2(x) exp2f(x)
#endif
#if __has_builtin(__builtin_amdgcn_rcpf)
#define RCP(x) __builtin_amdgcn_rcpf(x)     // bare v_rcp_f32 (2^-22 rel err)
#else
#define RCP(x) (1.0f / (x))
#endif

// d_ws layout
#define WS_QKVW 0                   // 288*96 bf16 = 55296 B (q rows prescaled)
#define WS_PROJW 55296              // 96*96 bf16  = 18432 B
#define WS_BIAS 73728               // 6*16*64 float4 = 98304 B (x log2e)
#define WS_TOTAL 172032

__device__ __forceinline__ f32x4 mfma32(bf16x8 a, bf16x8 b, f32x4 c) {
  return __builtin_amdgcn_mfma_f32_16x16x32_bf16(a, b, c, 0, 0, 0);
}
// K=16 MFMA. Fragment alignment facts (verified r7-r21):
//  * A/B fragment lane(l16,lq) holds row/col=l16, k=4*lq+e  — identical to
//    the W*X^T D-fragment (row=4lq+r, col=l16), so K,Q stay in registers.
//  * QK^T output s[a] = S[q=l16][kv=16a+4lq+r] — IS the PV A-frag chunk a.
//  * V-phase D-frag for mt=a IS the PV B-frag chunk a.
//  * r22: rowsum via mfma16k(pa[a], ones) lands in the SAME D-layout as the
//    PV output (same A operand, same instruction) -> rv[r] normalizes exactly
//    the row oacc[r] holds, BY CONSTRUCTION. This both fixes the r9-r21
//    cross-row normalization (shfl-tsum lived in the transposed layout;
//    passed only because rowsums are statistically near-uniform) and moves
//    ~33 VALU instrs/bq onto the MFMA pipe.
__device__ __forceinline__ f32x4 mfma16k(bf16x4 a, bf16x4 b, f32x4 c) {
  return __builtin_amdgcn_mfma_f32_16x16x16bf16_1k(
      __builtin_bit_cast(s16x4, a), __builtin_bit_cast(s16x4, b), c, 0, 0, 0);
}

__device__ __forceinline__ bf16x8 cvt8(const float* p) {
  const float4* q = (const float4*)p;
  float4 a = q[0];
  float4 b = q[1];
  bf16x8 r;
  r[0] = (__bf16)a.x; r[1] = (__bf16)a.y; r[2] = (__bf16)a.z; r[3] = (__bf16)a.w;
  r[4] = (__bf16)b.x; r[5] = (__bf16)b.y; r[6] = (__bf16)b.z; r[7] = (__bf16)b.w;
  return r;
}

// Pre-pass: weights -> bf16 (q rows x QS so QK logits arrive pre-scaled for
// exp2); bias gathered into MFMA-fragment order and x log2(e):
// bias[((h*16 + bq*4 + a)*64 + lane)*4 + r] = log2e * rpb[rpi[qrow*64+kcol]*6+h]
// (Replay-stable staging across r2/4/6/8/9/14/15/16/19/20/21.)
__global__ void prep_kernel(const float* __restrict__ qkv_w,
                            const float* __restrict__ proj_w,
                            const float* __restrict__ rpb,
                            const int* __restrict__ rpi,
                            char* __restrict__ ws) {
  int i = blockIdx.x * blockDim.x + threadIdx.x;
  __bf16* qw = (__bf16*)(ws + WS_QKVW);
  __bf16* pw = (__bf16*)(ws + WS_PROJW);
  float* bias = (float*)(ws + WS_BIAS);
  if (i < 288 * 96) {
    float v = qkv_w[i];
    if (i < 96 * 96) v *= QS;  // q feature rows: fold 0.25*log2e
    qw[i] = (__bf16)v;
  }
  int j = i - 288 * 96;
  if (j >= 0 && j < 96 * 96) pw[j] = (__bf16)proj_w[j];
  int t = i - (288 * 96 + 96 * 96);
  if (t >= 0 && t < HEADS * 16 * 64 * 4) {
    int r = t & 3;
    int lane = (t >> 2) & 63;
    int ba = (t >> 8) & 15;
    int h = t >> 12;
    int bq = ba >> 2, a = ba & 3;
    int l16 = lane & 15, lq = lane >> 4;
    int qrow = 16 * bq + l16;
    int kcol = 16 * a + 4 * lq + r;
    bias[t] = 1.4426950408889634f * rpb[rpi[qrow * 64 + kcol] * HEADS + h];
  }
}

// r22: r21 (75.9us, VALUBusy 35%) + mfma-ones rowsum. r21 proved the kernel
// responds to VALU cuts (-7% from exp2/rcp folding); softmax's tsum block
// (16 lshl + 15 fadd + 2 shfl per bq) is the next-fattest VALU chunk — moved
// to the MFMA pipe. Structure unchanged: 2-wave blocks, 3 heads/wave,
// 25600 B LDS, 2 barriers, ~72-80 VGPR (no spill).
template <bool USE_WS>
__global__ __launch_bounds__(128, 4) void win_attn(
    const float* __restrict__ x,
    const int* __restrict__ rpi,
    const float* __restrict__ qkv_w,
    const float* __restrict__ qkv_b,
    const float* __restrict__ proj_w,
    const float* __restrict__ proj_b,
    const float* __restrict__ rpb,
    const char* __restrict__ ws,
    float* __restrict__ out) {
  __shared__ __align__(16) __bf16 xfrag[6144];   // 12 frags * 512 bf16
  __shared__ __align__(16) __bf16 ao[64 * 104];  // 13312 B

  const int tid = (int)threadIdx.x;
  const int wv = tid >> 6;  // 0..1
  const int lane = tid & 63;
  const int l16 = lane & 15;
  const int lq = lane >> 4;
  const int b = (int)blockIdx.x;

  const float* xw = x + (size_t)b * (NTOK * DIM);
  const __bf16* qwb = (const __bf16*)(ws + WS_QKVW);
  const __bf16* pwb = (const __bf16*)(ws + WS_PROJW);

  bf16x4 ones4;
#pragma unroll
  for (int r = 0; r < 4; ++r) ones4[r] = (__bf16)1.0f;

  // ---- stage x fragments (wave wv does frags 6wv..6wv+5; mt,ks static) ----
#pragma unroll
  for (int ff = 0; ff < 6; ++ff) {
    const int mt = 2 * wv + ff / 3;
    const int ks = ff % 3;
    const int f = 6 * wv + ff;
    bf16x8 v = cvt8(xw + (16 * mt + l16) * DIM + 32 * ks + 8 * lq);
    *(bf16x8*)(xfrag + (f * 64 + lane) * 8) = v;
  }
  __syncthreads();

#define XV(mt, ks) (*(const bf16x8*)(xfrag + (((mt) * 3 + (ks)) * 64 + lane) * 8))

  // ---- 3 heads sequentially per wave; NO unroll (register discipline) ----
#pragma unroll 1
  for (int hh = 0; hh < 3; ++hh) {
    const int h = wv + 2 * hh;

    // K phase: D = Wk * X^T + kb (bias as C-init); D-frag stays in regs
    bf16x4 kb[4];
    {
      const int frow = (HEADS + h) * 16;
      bf16x8 wb[3];
#pragma unroll
      for (int ks = 0; ks < 3; ++ks) {
        if constexpr (USE_WS)
          wb[ks] = *(const bf16x8*)(qwb + (frow + l16) * 96 + 32 * ks + 8 * lq);
        else
          wb[ks] = cvt8(qkv_w + (frow + l16) * 96 + 32 * ks + 8 * lq);
      }
      const float4 kb4 = *(const float4*)(qkv_b + frow + 4 * lq);
#pragma unroll
      for (int mt = 0; mt < 4; ++mt) {
        f32x4 acc = {kb4.x, kb4.y, kb4.z, kb4.w};
#pragma unroll
        for (int ks = 0; ks < 3; ++ks) acc = mfma32(wb[ks], XV(mt, ks), acc);
#pragma unroll
        for (int r = 0; r < 4; ++r) kb[mt][r] = (__bf16)acc[r];
      }
    }

    // Q phase: D = Wq' * X^T + qb' (weights prescaled by QS in prep)
    bf16x4 qv4[4];
    {
      const int frow = h * 16;
      bf16x8 wb[3];
#pragma unroll
      for (int ks = 0; ks < 3; ++ks) {
        if constexpr (USE_WS)
          wb[ks] = *(const bf16x8*)(qwb + (frow + l16) * 96 + 32 * ks + 8 * lq);
        else
          wb[ks] = cvt8(qkv_w + (frow + l16) * 96 + 32 * ks + 8 * lq);
      }
      const float4 qb4 = *(const float4*)(qkv_b + frow + 4 * lq);
#pragma unroll
      for (int mt = 0; mt < 4; ++mt) {
        f32x4 acc;
        if constexpr (USE_WS) {
          acc[0] = qb4.x * QS; acc[1] = qb4.y * QS;
          acc[2] = qb4.z * QS; acc[3] = qb4.w * QS;
        } else {
          acc[0] = qb4.x; acc[1] = qb4.y; acc[2] = qb4.z; acc[3] = qb4.w;
        }
#pragma unroll
        for (int ks = 0; ks < 3; ++ks) acc = mfma32(wb[ks], XV(mt, ks), acc);
#pragma unroll
        for (int r = 0; r < 4; ++r) {
          if constexpr (USE_WS)
            qv4[mt][r] = (__bf16)acc[r];          // scale already in weights
          else
            qv4[mt][r] = (__bf16)(acc[r] * QS);   // fallback: scale here
        }
      }
    }

    // V phase: D = X * Wv^T + vb (col-bias broadcast C-init)
    bf16x4 vb4[4];
    {
      const int frow = (2 * HEADS + h) * 16;
      bf16x8 wb[3];
#pragma unroll
      for (int ks = 0; ks < 3; ++ks) {
        if constexpr (USE_WS)
          wb[ks] = *(const bf16x8*)(qwb + (frow + l16) * 96 + 32 * ks + 8 * lq);
        else
          wb[ks] = cvt8(qkv_w + (frow + l16) * 96 + 32 * ks + 8 * lq);
      }
      const float vb = qkv_b[frow + l16];
#pragma unroll
      for (int mt = 0; mt < 4; ++mt) {
        f32x4 acc = {vb, vb, vb, vb};
#pragma unroll
        for (int ks = 0; ks < 3; ++ks) acc = mfma32(XV(mt, ks), wb[ks], acc);
#pragma unroll
        for (int r = 0; r < 4; ++r) vb4[mt][r] = (__bf16)acc[r];
      }
    }

    // attention per q-tile: pure register dataflow
    const float4* bias4 = (const float4*)(ws + WS_BIAS) + (h << 10);
#pragma unroll
    for (int bq = 0; bq < 4; ++bq) {
      f32x4 s[4];
      if constexpr (USE_WS) {
#pragma unroll
        for (int a = 0; a < 4; ++a)
          s[a] = __builtin_bit_cast(f32x4, bias4[(bq * 4 + a) * 64 + lane]);
      } else {
#pragma unroll
        for (int a = 0; a < 4; ++a)
#pragma unroll
          for (int r = 0; r < 4; ++r)
            s[a][r] = 1.4426950408889634f *
                      rpb[rpi[(16 * bq + l16) * 64 + 16 * a + 4 * lq + r] *
                              HEADS + h];
      }

      // QK^T: S^T = K * Q^T with (log2e-scaled) bias as C-init
#pragma unroll
      for (int a = 0; a < 4; ++a) s[a] = mfma16k(kb[a], qv4[bq], s[a]);

      // P = exp2(S) in bf16 (logits pre-scaled by log2e -> bare v_exp_f32)
      bf16x4 pa[4];
#pragma unroll
      for (int a = 0; a < 4; ++a)
#pragma unroll
        for (int r = 0; r < 4; ++r) pa[a][r] = (__bf16)EXP2(s[a][r]);

      // PV and rowsum together on the MFMA pipe; identical D-layouts
      // (same A operand, same instruction) -> rv[r] matches oacc[r]'s row.
      f32x4 oacc = {0.f, 0.f, 0.f, 0.f};
      f32x4 tsum4 = {0.f, 0.f, 0.f, 0.f};
#pragma unroll
      for (int a = 0; a < 4; ++a) {
        oacc = mfma16k(pa[a], vb4[a], oacc);
        tsum4 = mfma16k(pa[a], ones4, tsum4);
      }

#pragma unroll
      for (int r = 0; r < 4; ++r)
        ao[(16 * bq + 4 * lq + r) * 104 + 16 * h + l16] =
            (__bf16)(oacc[r] * RCP(tsum4[r]));
    }
  }
#undef XV
  __syncthreads();  // ao complete (xfrag disjoint: no overlay hazard)

  // ---- proj: 3 column-tiles per wave (c = wv, wv+2, wv+4); no hoisting ----
  float* outw = out + (size_t)b * (NTOK * DIM);
#pragma unroll 1
  for (int cc = 0; cc < 3; ++cc) {
    const int c = wv + 2 * cc;
    bf16x8 wpb[3];
#pragma unroll
    for (int ks = 0; ks < 3; ++ks) {
      if constexpr (USE_WS)
        wpb[ks] = *(const bf16x8*)(pwb + (16 * c + l16) * 96 + 32 * ks + 8 * lq);
      else
        wpb[ks] = cvt8(proj_w + (16 * c + l16) * 96 + 32 * ks + 8 * lq);
    }
    const float pb2 = proj_b[16 * c + l16];
#pragma unroll
    for (int mt = 0; mt < 4; ++mt) {
      f32x4 acc = {pb2, pb2, pb2, pb2};  // bias C-init (per-col broadcast)
#pragma unroll
      for (int ks = 0; ks < 3; ++ks) {
        bf16x8 aa =
            *(const bf16x8*)(ao + (16 * mt + l16) * 104 + 32 * ks + 8 * lq);
        acc = mfma32(aa, wpb[ks], acc);
      }
#pragma unroll
      for (int r = 0; r < 4; ++r)
        outw[(16 * mt + 4 * lq + r) * 96 + 16 * c + l16] = acc[r];
    }
  }
}

extern "C" void kernel_launch(void* const* d_in, const int* in_sizes, int n_in,
                              void* d_out, int out_size, void* d_ws, size_t ws_size,
                              hipStream_t stream) {
  const float* x      = (const float*)d_in[0];
  const int*   rpi    = (const int*)d_in[1];
  const float* qkv_w  = (const float*)d_in[2];
  const float* qkv_b  = (const float*)d_in[3];
  const float* proj_w = (const float*)d_in[4];
  const float* proj_b = (const float*)d_in[5];
  const float* rpb    = (const float*)d_in[6];
  float* out = (float*)d_out;

  if (ws_size >= (size_t)WS_TOTAL) {
    prep_kernel<<<240, 256, 0, stream>>>(qkv_w, proj_w, rpb, rpi, (char*)d_ws);
    win_attn<true><<<NWIN, 128, 0, stream>>>(x, rpi, qkv_w, qkv_b, proj_w,
                                             proj_b, rpb, (const char*)d_ws,
                                             out);
  } else {
    win_attn<false><<<NWIN, 128, 0, stream>>>(x, rpi, qkv_w, qkv_b, proj_w,
                                              proj_b, rpb, (const char*)d_ws,
                                              out);
  }
}

// Round 23
// 71.386 us; speedup vs baseline: 2.7428x; 1.0354x over previous
//
#include <hip/hip_runtime.h>

#define NWIN 4096
#define DIM 96
#define HEADS 6
#define NTOK 64
#define QS 0.36067376022224085f  // 0.25 * log2(e): folded into q-weights/bias

typedef __bf16 bf16x8 __attribute__((ext_vector_type(8)));
typedef __bf16 bf16x4 __attribute__((ext_vector_type(4)));
typedef short  s16x4  __attribute__((ext_vector_type(4)));
typedef float  f32x4  __attribute__((ext_vector_type(4)));

#if __has_builtin(__builtin_amdgcn_exp2f)
#define EXP2(x) __builtin_amdgcn_exp2f(x)   // bare v_exp_f32, no libm wrapper
#else
#define EXP2(x) exp2f(x)
#endif
#if __has_builtin(__builtin_amdgcn_rcpf)
#define RCP(x) __builtin_amdgcn_rcpf(x)     // bare v_rcp_f32 (2^-22 rel err)
#else
#define RCP(x) (1.0f / (x))
#endif

// d_ws layout
#define WS_QKVW 0                   // 288*96 bf16 = 55296 B (q rows prescaled)
#define WS_PROJW 55296              // 96*96 bf16  = 18432 B
#define WS_BIAS 73728               // 6*16*64 float4 = 98304 B (x log2e)
#define WS_TOTAL 172032

__device__ __forceinline__ f32x4 mfma32(bf16x8 a, bf16x8 b, f32x4 c) {
  return __builtin_amdgcn_mfma_f32_16x16x32_bf16(a, b, c, 0, 0, 0);
}
// K=16 MFMA. Fragment alignment facts (verified r7-r22):
//  * A/B fragment lane(l16,lq) holds row/col=l16, k=4*lq+e  — identical to
//    the W*X^T D-fragment (row=4lq+r, col=l16), so K,Q stay in registers.
//  * QK^T output s[a] = S[q=l16][kv=16a+4lq+r] — IS the PV A-frag chunk a.
//  * V-phase D-frag for mt=a IS the PV B-frag chunk a.
//  * rowsum via mfma16k(pa[a], ones) lands in the SAME D-layout as the PV
//    output -> rv[r] normalizes exactly the row oacc[r] holds (r22-proven:
//    absmax 1.22e-4).
__device__ __forceinline__ f32x4 mfma16k(bf16x4 a, bf16x4 b, f32x4 c) {
  return __builtin_amdgcn_mfma_f32_16x16x16bf16_1k(
      __builtin_bit_cast(s16x4, a), __builtin_bit_cast(s16x4, b), c, 0, 0, 0);
}

__device__ __forceinline__ bf16x8 cvt8(const float* p) {
  const float4* q = (const float4*)p;
  float4 a = q[0];
  float4 b = q[1];
  bf16x8 r;
  r[0] = (__bf16)a.x; r[1] = (__bf16)a.y; r[2] = (__bf16)a.z; r[3] = (__bf16)a.w;
  r[4] = (__bf16)b.x; r[5] = (__bf16)b.y; r[6] = (__bf16)b.z; r[7] = (__bf16)b.w;
  return r;
}

// Pre-pass: weights -> bf16 (q rows x QS so QK logits arrive pre-scaled for
// exp2); bias gathered into MFMA-fragment order and x log2(e):
// bias[((h*16 + bq*4 + a)*64 + lane)*4 + r] = log2e * rpb[rpi[qrow*64+kcol]*6+h]
// (Replay-stable staging across r2/4/6/8/9/14/15/16/19/20/21/22.)
__global__ void prep_kernel(const float* __restrict__ qkv_w,
                            const float* __restrict__ proj_w,
                            const float* __restrict__ rpb,
                            const int* __restrict__ rpi,
                            char* __restrict__ ws) {
  int i = blockIdx.x * blockDim.x + threadIdx.x;
  __bf16* qw = (__bf16*)(ws + WS_QKVW);
  __bf16* pw = (__bf16*)(ws + WS_PROJW);
  float* bias = (float*)(ws + WS_BIAS);
  if (i < 288 * 96) {
    float v = qkv_w[i];
    if (i < 96 * 96) v *= QS;  // q feature rows: fold 0.25*log2e
    qw[i] = (__bf16)v;
  }
  int j = i - 288 * 96;
  if (j >= 0 && j < 96 * 96) pw[j] = (__bf16)proj_w[j];
  int t = i - (288 * 96 + 96 * 96);
  if (t >= 0 && t < HEADS * 16 * 64 * 4) {
    int r = t & 3;
    int lane = (t >> 2) & 63;
    int ba = (t >> 8) & 15;
    int h = t >> 12;
    int bq = ba >> 2, a = ba & 3;
    int l16 = lane & 15, lq = lane >> 4;
    int qrow = 16 * bq + l16;
    int kcol = 16 * a + 4 * lq + r;
    bias[t] = 1.4426950408889634f * rpb[rpi[qrow * 64 + kcol] * HEADS + h];
  }
}

// r23: r22 (73.9us, VALUBusy 32%, absmax 1.22e-4) + bias prefetch distance-1.
// The QK^T C-init is 4 global_load_dwordx4 from d_ws issued right before the
// mfma16k chain that consumes them — 12 exposed L2 load->use chains per wave
// at only ~9 resident waves/CU. Double-buffer (bc/bn, r8 pattern): bq+1's
// bias loads issue before bq's softmax/PV, hiding the latency; only the
// first batch per head stays exposed. +16-32 transient regs (68 -> ~90,
// budget 128 at launch_bounds(128,4)). Everything else identical to r22.
template <bool USE_WS>
__global__ __launch_bounds__(128, 4) void win_attn(
    const float* __restrict__ x,
    const int* __restrict__ rpi,
    const float* __restrict__ qkv_w,
    const float* __restrict__ qkv_b,
    const float* __restrict__ proj_w,
    const float* __restrict__ proj_b,
    const float* __restrict__ rpb,
    const char* __restrict__ ws,
    float* __restrict__ out) {
  __shared__ __align__(16) __bf16 xfrag[6144];   // 12 frags * 512 bf16
  __shared__ __align__(16) __bf16 ao[64 * 104];  // 13312 B

  const int tid = (int)threadIdx.x;
  const int wv = tid >> 6;  // 0..1
  const int lane = tid & 63;
  const int l16 = lane & 15;
  const int lq = lane >> 4;
  const int b = (int)blockIdx.x;

  const float* xw = x + (size_t)b * (NTOK * DIM);
  const __bf16* qwb = (const __bf16*)(ws + WS_QKVW);
  const __bf16* pwb = (const __bf16*)(ws + WS_PROJW);

  bf16x4 ones4;
#pragma unroll
  for (int r = 0; r < 4; ++r) ones4[r] = (__bf16)1.0f;

  // ---- stage x fragments (wave wv does frags 6wv..6wv+5; mt,ks static) ----
#pragma unroll
  for (int ff = 0; ff < 6; ++ff) {
    const int mt = 2 * wv + ff / 3;
    const int ks = ff % 3;
    const int f = 6 * wv + ff;
    bf16x8 v = cvt8(xw + (16 * mt + l16) * DIM + 32 * ks + 8 * lq);
    *(bf16x8*)(xfrag + (f * 64 + lane) * 8) = v;
  }
  __syncthreads();

#define XV(mt, ks) (*(const bf16x8*)(xfrag + (((mt) * 3 + (ks)) * 64 + lane) * 8))

  // ---- 3 heads sequentially per wave; NO unroll (register discipline) ----
#pragma unroll 1
  for (int hh = 0; hh < 3; ++hh) {
    const int h = wv + 2 * hh;

    // K phase: D = Wk * X^T + kb (bias as C-init); D-frag stays in regs
    bf16x4 kb[4];
    {
      const int frow = (HEADS + h) * 16;
      bf16x8 wb[3];
#pragma unroll
      for (int ks = 0; ks < 3; ++ks) {
        if constexpr (USE_WS)
          wb[ks] = *(const bf16x8*)(qwb + (frow + l16) * 96 + 32 * ks + 8 * lq);
        else
          wb[ks] = cvt8(qkv_w + (frow + l16) * 96 + 32 * ks + 8 * lq);
      }
      const float4 kb4 = *(const float4*)(qkv_b + frow + 4 * lq);
#pragma unroll
      for (int mt = 0; mt < 4; ++mt) {
        f32x4 acc = {kb4.x, kb4.y, kb4.z, kb4.w};
#pragma unroll
        for (int ks = 0; ks < 3; ++ks) acc = mfma32(wb[ks], XV(mt, ks), acc);
#pragma unroll
        for (int r = 0; r < 4; ++r) kb[mt][r] = (__bf16)acc[r];
      }
    }

    // Q phase: D = Wq' * X^T + qb' (weights prescaled by QS in prep)
    bf16x4 qv4[4];
    {
      const int frow = h * 16;
      bf16x8 wb[3];
#pragma unroll
      for (int ks = 0; ks < 3; ++ks) {
        if constexpr (USE_WS)
          wb[ks] = *(const bf16x8*)(qwb + (frow + l16) * 96 + 32 * ks + 8 * lq);
        else
          wb[ks] = cvt8(qkv_w + (frow + l16) * 96 + 32 * ks + 8 * lq);
      }
      const float4 qb4 = *(const float4*)(qkv_b + frow + 4 * lq);
#pragma unroll
      for (int mt = 0; mt < 4; ++mt) {
        f32x4 acc;
        if constexpr (USE_WS) {
          acc[0] = qb4.x * QS; acc[1] = qb4.y * QS;
          acc[2] = qb4.z * QS; acc[3] = qb4.w * QS;
        } else {
          acc[0] = qb4.x; acc[1] = qb4.y; acc[2] = qb4.z; acc[3] = qb4.w;
        }
#pragma unroll
        for (int ks = 0; ks < 3; ++ks) acc = mfma32(wb[ks], XV(mt, ks), acc);
#pragma unroll
        for (int r = 0; r < 4; ++r) {
          if constexpr (USE_WS)
            qv4[mt][r] = (__bf16)acc[r];          // scale already in weights
          else
            qv4[mt][r] = (__bf16)(acc[r] * QS);   // fallback: scale here
        }
      }
    }

    // V phase: D = X * Wv^T + vb (col-bias broadcast C-init)
    bf16x4 vb4[4];
    {
      const int frow = (2 * HEADS + h) * 16;
      bf16x8 wb[3];
#pragma unroll
      for (int ks = 0; ks < 3; ++ks) {
        if constexpr (USE_WS)
          wb[ks] = *(const bf16x8*)(qwb + (frow + l16) * 96 + 32 * ks + 8 * lq);
        else
          wb[ks] = cvt8(qkv_w + (frow + l16) * 96 + 32 * ks + 8 * lq);
      }
      const float vb = qkv_b[frow + l16];
#pragma unroll
      for (int mt = 0; mt < 4; ++mt) {
        f32x4 acc = {vb, vb, vb, vb};
#pragma unroll
        for (int ks = 0; ks < 3; ++ks) acc = mfma32(XV(mt, ks), wb[ks], acc);
#pragma unroll
        for (int r = 0; r < 4; ++r) vb4[mt][r] = (__bf16)acc[r];
      }
    }

    // attention per q-tile: pure register dataflow; bias double-buffered
    const float4* bias4 = (const float4*)(ws + WS_BIAS) + (h << 10);
    f32x4 bc[4];  // current tile's bias (C-init)
    if constexpr (USE_WS) {
#pragma unroll
      for (int a = 0; a < 4; ++a)
        bc[a] = __builtin_bit_cast(f32x4, bias4[a * 64 + lane]);
    }

#pragma unroll
    for (int bq = 0; bq < 4; ++bq) {
      f32x4 s[4];
      if constexpr (USE_WS) {
#pragma unroll
        for (int a = 0; a < 4; ++a) s[a] = bc[a];
        // prefetch bq+1's bias: issues before softmax/PV, lands by next QK
        if (bq < 3) {
#pragma unroll
          for (int a = 0; a < 4; ++a)
            bc[a] = __builtin_bit_cast(f32x4,
                                       bias4[((bq + 1) * 4 + a) * 64 + lane]);
        }
      } else {
#pragma unroll
        for (int a = 0; a < 4; ++a)
#pragma unroll
          for (int r = 0; r < 4; ++r)
            s[a][r] = 1.4426950408889634f *
                      rpb[rpi[(16 * bq + l16) * 64 + 16 * a + 4 * lq + r] *
                              HEADS + h];
      }

      // QK^T: S^T = K * Q^T with (log2e-scaled) bias as C-init
#pragma unroll
      for (int a = 0; a < 4; ++a) s[a] = mfma16k(kb[a], qv4[bq], s[a]);

      // P = exp2(S) in bf16 (logits pre-scaled by log2e -> bare v_exp_f32)
      bf16x4 pa[4];
#pragma unroll
      for (int a = 0; a < 4; ++a)
#pragma unroll
        for (int r = 0; r < 4; ++r) pa[a][r] = (__bf16)EXP2(s[a][r]);

      // PV and rowsum together on the MFMA pipe; identical D-layouts
      f32x4 oacc = {0.f, 0.f, 0.f, 0.f};
      f32x4 tsum4 = {0.f, 0.f, 0.f, 0.f};
#pragma unroll
      for (int a = 0; a < 4; ++a) {
        oacc = mfma16k(pa[a], vb4[a], oacc);
        tsum4 = mfma16k(pa[a], ones4, tsum4);
      }

#pragma unroll
      for (int r = 0; r < 4; ++r)
        ao[(16 * bq + 4 * lq + r) * 104 + 16 * h + l16] =
            (__bf16)(oacc[r] * RCP(tsum4[r]));
    }
  }
#undef XV
  __syncthreads();  // ao complete (xfrag disjoint: no overlay hazard)

  // ---- proj: 3 column-tiles per wave (c = wv, wv+2, wv+4); no hoisting ----
  float* outw = out + (size_t)b * (NTOK * DIM);
#pragma unroll 1
  for (int cc = 0; cc < 3; ++cc) {
    const int c = wv + 2 * cc;
    bf16x8 wpb[3];
#pragma unroll
    for (int ks = 0; ks < 3; ++ks) {
      if constexpr (USE_WS)
        wpb[ks] = *(const bf16x8*)(pwb + (16 * c + l16) * 96 + 32 * ks + 8 * lq);
      else
        wpb[ks] = cvt8(proj_w + (16 * c + l16) * 96 + 32 * ks + 8 * lq);
    }
    const float pb2 = proj_b[16 * c + l16];
#pragma unroll
    for (int mt = 0; mt < 4; ++mt) {
      f32x4 acc = {pb2, pb2, pb2, pb2};  // bias C-init (per-col broadcast)
#pragma unroll
      for (int ks = 0; ks < 3; ++ks) {
        bf16x8 aa =
            *(const bf16x8*)(ao + (16 * mt + l16) * 104 + 32 * ks + 8 * lq);
        acc = mfma32(aa, wpb[ks], acc);
      }
#pragma unroll
      for (int r = 0; r < 4; ++r)
        outw[(16 * mt + 4 * lq + r) * 96 + 16 * c + l16] = acc[r];
    }
  }
}

extern "C" void kernel_launch(void* const* d_in, const int* in_sizes, int n_in,
                              void* d_out, int out_size, void* d_ws, size_t ws_size,
                              hipStream_t stream) {
  const float* x      = (const float*)d_in[0];
  const int*   rpi    = (const int*)d_in[1];
  const float* qkv_w  = (const float*)d_in[2];
  const float* qkv_b  = (const float*)d_in[3];
  const float* proj_w = (const float*)d_in[4];
  const float* proj_b = (const float*)d_in[5];
  const float* rpb    = (const float*)d_in[6];
  float* out = (float*)d_out;

  if (ws_size >= (size_t)WS_TOTAL) {
    prep_kernel<<<240, 256, 0, stream>>>(qkv_w, proj_w, rpb, rpi, (char*)d_ws);
    win_attn<true><<<NWIN, 128, 0, stream>>>(x, rpi, qkv_w, qkv_b, proj_w,
                                             proj_b, rpb, (const char*)d_ws,
                                             out);
  } else {
    win_attn<false><<<NWIN, 128, 0, stream>>>(x, rpi, qkv_w, qkv_b, proj_w,
                                              proj_b, rpb, (const char*)d_ws,
                                              out);
  }
}